// Round 13
// baseline (32.765 us; speedup 1.0000x reference)
//
#include <hip/hip_runtime.h>
#include <math.h>

#define NB 2048
#define ND 784
#define NK 128
#define KP 3136            // 4*784: K = 4d+c, A slots {m*x^2, m*x, m, 0}
#define NSTEP 98           // KP/32 k-steps
#define KSPLIT 7           // K-chunks -> partials
#define SPK 14             // k-steps per chunk
#define MT 64              // rows per k_mm block (4 waves x 16 rows)
#define NHALF 4            // N-split: each wave does 2 nt = 32 cols

typedef __attribute__((ext_vector_type(8))) short short8;
typedef __attribute__((ext_vector_type(4))) float f32x4;

// ws float offsets:
#define OFF_LW   0
#define OFF_PART 128
#define N_PART   (KSPLIT * NB * NK)       // 1,835,008 floats (7.3 MB)
#define OFF_BH   (OFF_PART + N_PART)
#define N_B_F    (NSTEP * 8 * 64 * 4)     // 200,704 float slots per table
#define OFF_BL   (OFF_BH + N_B_F)
// total ~2.24M floats ~= 9 MB

__device__ inline ushort f2bf(float f) {   // round-to-nearest-even f32->bf16
  uint u = __float_as_uint(f);
  return (ushort)((u + 0x7FFFu + ((u >> 16) & 1u)) >> 16);
}

// B-prep + log w. Fragment fid = ks*8 + nt; lane l holds
// B[K = ks*32 + (l>>4)*8 + j][n = nt*16 + (l&15)], j=0..7, K = 4d+c:
// c==0 -> -1/2c, c==1 -> mu/c, c==2 -> -mu^2/2c - ln(c)/2, c==3 -> 0.
__global__ __launch_bounds__(256) void k_prep(
    const float* __restrict__ w, const float* __restrict__ mu,
    const float* __restrict__ cov, float* __restrict__ ws) {
  int tid = blockIdx.x * 256 + threadIdx.x;   // 0..50175
  if (tid < NK) ws[OFF_LW + tid] = logf(w[tid]);
  int l   = tid & 63;
  int fid = tid >> 6;          // 0..783
  int nt  = fid & 7;
  int ks  = fid >> 3;          // 0..97
  int n   = nt * 16 + (l & 15);
  int K0  = ks * 32 + ((l >> 4) << 3);
  ushort hi[8], lo[8];
#pragma unroll
  for (int j = 0; j < 8; j++) {
    int K = K0 + j;
    int d = K >> 2;
    int c = K & 3;
    float cv = cov[n * ND + d];
    float mv = mu[n * ND + d];
    float v = (c == 0) ? (-0.5f / cv)
            : (c == 1) ? (mv / cv)
            : (c == 2) ? (-mv * mv * 0.5f / cv - 0.5f * logf(cv))
                       : 0.f;
    ushort h = f2bf(v);
    hi[j] = h;
    lo[j] = f2bf(v - __uint_as_float(((uint)h) << 16));
  }
  uint4 vh, vl;
  vh.x = (uint)hi[0] | ((uint)hi[1] << 16);
  vh.y = (uint)hi[2] | ((uint)hi[3] << 16);
  vh.z = (uint)hi[4] | ((uint)hi[5] << 16);
  vh.w = (uint)hi[6] | ((uint)hi[7] << 16);
  vl.x = (uint)lo[0] | ((uint)lo[1] << 16);
  vl.y = (uint)lo[2] | ((uint)lo[3] << 16);
  vl.z = (uint)lo[4] | ((uint)lo[5] << 16);
  vl.w = (uint)lo[6] | ((uint)lo[7] << 16);
  ((uint4*)(ws + OFF_BH))[fid * 64 + l] = vh;
  ((uint4*)(ws + OFF_BL))[fid * 64 + l] = vl;
}

// GEMM, fused A-conversion, N-split 4, depth-2 pipeline:
// grid = 32 mt x NHALF x KSPLIT = 896 blocks, 4 waves (3.5 waves/SIMD).
// Wave: 16 rows x 32 cols (nt = nh*2, nh*2+1) x SPK=14 k-steps; partials
// halve vs KSPLIT=14 while TLP stays at R12's proven level.
// acc layout (m89): col = lane&15, row = (lane>>4)*4 + reg.
__global__ __launch_bounds__(256, 3) void k_mm(
    const float* __restrict__ data, const float* __restrict__ mask,
    float* __restrict__ ws) {
  const short8* Bh = (const short8*)(ws + OFF_BH);
  const short8* Bl = (const short8*)(ws + OFF_BL);
  float* part = ws + OFF_PART;

  int bid = blockIdx.x;
  int mt  = bid / (NHALF * KSPLIT);
  int rem = bid % (NHALF * KSPLIT);
  int nh  = rem / KSPLIT;
  int kc  = rem % KSPLIT;
  int w   = threadIdx.x >> 6;
  int l   = threadIdx.x & 63;
  int r0  = mt * MT + w * 16;
  int rowA = r0 + (l & 15);
  int g2   = (l >> 4) << 1;     // dim offset within k-step: 0,2,4,6
  int n0   = nh * 2;            // first nt of this wave

  f32x4 acc[2];
  acc[0] = (f32x4){0.f, 0.f, 0.f, 0.f};
  acc[1] = (f32x4){0.f, 0.f, 0.f, 0.f};

  const float* dp = data + (size_t)rowA * ND + g2;
  const float* mp = mask + (size_t)rowA * ND + g2;

  short8 Bhb[2][2], Blb[2][2];
  float2 xb[2], mb[2];

  auto loadstep = [&](int s, int buf) {
    int ks = kc * SPK + s;
    const short8* bh = Bh + ((size_t)(ks * 8) + n0) * 64 + l;
    const short8* bl = Bl + ((size_t)(ks * 8) + n0) * 64 + l;
    Bhb[buf][0] = bh[0];  Bhb[buf][1] = bh[64];
    Blb[buf][0] = bl[0];  Blb[buf][1] = bl[64];
    xb[buf] = *(const float2*)(dp + ks * 8);
    mb[buf] = *(const float2*)(mp + ks * 8);
  };

  loadstep(0, 0);

#pragma unroll
  for (int s = 0; s < SPK; s++) {
    const int cur = s & 1;
    const int nxt = cur ^ 1;
    if (s + 1 < SPK) loadstep(s + 1, nxt);   // in flight during this step

    float2 x = xb[cur], m = mb[cur];
    float mx0 = m.x * x.x, mq0 = mx0 * x.x;
    float mx1 = m.y * x.y, mq1 = mx1 * x.y;
    ushort h_q0 = f2bf(mq0), h_x0 = f2bf(mx0);
    ushort h_q1 = f2bf(mq1), h_x1 = f2bf(mx1);
    ushort h_m0 = (ushort)(__float_as_uint(m.x) >> 16);  // exact: m in {0,1}
    ushort h_m1 = (ushort)(__float_as_uint(m.y) >> 16);
    float r_q0 = mq0 - __uint_as_float(((uint)h_q0) << 16);
    float r_x0 = mx0 - __uint_as_float(((uint)h_x0) << 16);
    float r_q1 = mq1 - __uint_as_float(((uint)h_q1) << 16);
    float r_x1 = mx1 - __uint_as_float(((uint)h_x1) << 16);

    short8 a_h, a_l;
    a_h[0] = (short)h_q0;       a_h[1] = (short)h_x0;
    a_h[2] = (short)h_m0;       a_h[3] = 0;
    a_h[4] = (short)h_q1;       a_h[5] = (short)h_x1;
    a_h[6] = (short)h_m1;       a_h[7] = 0;
    a_l[0] = (short)f2bf(r_q0); a_l[1] = (short)f2bf(r_x0);
    a_l[2] = 0;                 a_l[3] = 0;
    a_l[4] = (short)f2bf(r_q1); a_l[5] = (short)f2bf(r_x1);
    a_l[6] = 0;                 a_l[7] = 0;

    acc[0] = __builtin_amdgcn_mfma_f32_16x16x32_bf16(a_h, Bhb[cur][0], acc[0], 0, 0, 0);
    acc[0] = __builtin_amdgcn_mfma_f32_16x16x32_bf16(a_h, Blb[cur][0], acc[0], 0, 0, 0);
    acc[0] = __builtin_amdgcn_mfma_f32_16x16x32_bf16(a_l, Bhb[cur][0], acc[0], 0, 0, 0);
    acc[1] = __builtin_amdgcn_mfma_f32_16x16x32_bf16(a_h, Bhb[cur][1], acc[1], 0, 0, 0);
    acc[1] = __builtin_amdgcn_mfma_f32_16x16x32_bf16(a_h, Blb[cur][1], acc[1], 0, 0, 0);
    acc[1] = __builtin_amdgcn_mfma_f32_16x16x32_bf16(a_l, Bhb[cur][1], acc[1], 0, 0, 0);
  }

#pragma unroll
  for (int ntl = 0; ntl < 2; ntl++)
#pragma unroll
    for (int r = 0; r < 4; r++) {
      int grow = r0 + ((l >> 4) << 2) + r;
      part[((size_t)kc * NB + grow) * NK + (n0 + ntl) * 16 + (l & 15)] = acc[ntl][r];
    }
}

// 2 rows per wave, float4 per lane (k-quad). Reduce KSPLIT partials, +log w,
// NaN fix, LSE with the reference's per-term +1e-8 (4e-8 per lane), exp.
__global__ __launch_bounds__(256) void k_final(
    const float* __restrict__ ws, float* __restrict__ out) {
  const float4* lw4   = (const float4*)(ws + OFF_LW);
  const float4* part4 = (const float4*)(ws + OFF_PART);
  int lane = threadIdx.x & 63;
  int wv   = threadIdx.x >> 6;
  int half = lane >> 5;
  int lk   = lane & 31;
  int b = blockIdx.x * 8 + wv * 2 + half;

  float4 s = make_float4(0.f, 0.f, 0.f, 0.f);
#pragma unroll
  for (int sp = 0; sp < KSPLIT; sp++) {
    float4 v = part4[((size_t)sp * NB + b) * 32 + lk];
    s.x += v.x; s.y += v.y; s.z += v.z; s.w += v.w;
  }
  float4 lv = lw4[lk];
  s.x += lv.x; s.y += lv.y; s.z += lv.z; s.w += lv.w;
  if (isnan(s.x)) s.x = 0.f;
  if (isnan(s.y)) s.y = 0.f;
  if (isnan(s.z)) s.z = 0.f;
  if (isnan(s.w)) s.w = 0.f;

  float mx = fmaxf(fmaxf(s.x, s.y), fmaxf(s.z, s.w));
#pragma unroll
  for (int off = 16; off; off >>= 1) mx = fmaxf(mx, __shfl_xor(mx, off));
  float sum = expf(s.x - mx) + expf(s.y - mx) + expf(s.z - mx) + expf(s.w - mx) + 4e-8f;
#pragma unroll
  for (int off = 16; off; off >>= 1) sum += __shfl_xor(sum, off);
  float lse = logf(sum) + mx;
  float4 o = make_float4(expf(s.x - lse), expf(s.y - lse),
                         expf(s.z - lse), expf(s.w - lse));
  ((float4*)out)[(size_t)b * 32 + lk] = o;
}

extern "C" void kernel_launch(void* const* d_in, const int* in_sizes, int n_in,
                              void* d_out, int out_size, void* d_ws, size_t ws_size,
                              hipStream_t stream) {
  const float* data = (const float*)d_in[0];
  const float* mask = (const float*)d_in[1];
  const float* wts  = (const float*)d_in[2];
  const float* mu   = (const float*)d_in[3];
  const float* cov  = (const float*)d_in[4];
  float* ws  = (float*)d_ws;
  float* out = (float*)d_out;

  k_prep<<<196, 256, 0, stream>>>(wts, mu, cov, ws);
  k_mm<<<32 * NHALF * KSPLIT, 256, 0, stream>>>(data, mask, ws);
  k_final<<<NB / 8, 256, 0, stream>>>(ws, out);
}

// Round 14
// 30.881 us; speedup vs baseline: 1.0610x; 1.0610x over previous
//
#include <hip/hip_runtime.h>
#include <math.h>

#define NB 2048
#define ND 784
#define NK 128
#define KP 3136            // 4*784: K = 4d+c, A slots {m*x^2, m*x, m, 0}
#define NSTEP 98           // KP/32 k-steps
#define KSPLIT 14          // K-chunks -> partials
#define SPK 7              // k-steps per chunk
#define NGRID 896          // kc(14) x mt(32) x nn(2)

typedef __attribute__((ext_vector_type(8))) short short8;
typedef __attribute__((ext_vector_type(4))) float f32x4;

// ws float offsets:
#define OFF_LW   0
#define OFF_PART 128
#define N_PART   (KSPLIT * NB * NK)       // 3,670,016 floats (14.7 MB)
#define OFF_BH   (OFF_PART + N_PART)
#define N_B_F    (NSTEP * 8 * 64 * 4)     // 200,704 float slots per table
#define OFF_BL   (OFF_BH + N_B_F)

__device__ inline ushort f2bf(float f) {   // round-to-nearest-even f32->bf16
  uint u = __float_as_uint(f);
  return (ushort)((u + 0x7FFFu + ((u >> 16) & 1u)) >> 16);
}

// B-prep + log w. Fragment fid = ks*8 + nt; lane l holds
// B[K = ks*32 + (l>>4)*8 + j][n = nt*16 + (l&15)], j=0..7, K = 4d+c:
// c==0 -> -1/2c, c==1 -> mu/c, c==2 -> -mu^2/2c - ln(c)/2, c==3 -> 0.
__global__ __launch_bounds__(256) void k_prep(
    const float* __restrict__ w, const float* __restrict__ mu,
    const float* __restrict__ cov, float* __restrict__ ws) {
  int tid = blockIdx.x * 256 + threadIdx.x;   // 0..50175
  if (tid < NK) ws[OFF_LW + tid] = logf(w[tid]);
  int l   = tid & 63;
  int fid = tid >> 6;          // 0..783
  int nt  = fid & 7;
  int ks  = fid >> 3;          // 0..97
  int n   = nt * 16 + (l & 15);
  int K0  = ks * 32 + ((l >> 4) << 3);
  ushort hi[8], lo[8];
#pragma unroll
  for (int j = 0; j < 8; j++) {
    int K = K0 + j;
    int d = K >> 2;
    int c = K & 3;
    float cv = cov[n * ND + d];
    float mv = mu[n * ND + d];
    float v = (c == 0) ? (-0.5f / cv)
            : (c == 1) ? (mv / cv)
            : (c == 2) ? (-mv * mv * 0.5f / cv - 0.5f * logf(cv))
                       : 0.f;
    ushort h = f2bf(v);
    hi[j] = h;
    lo[j] = f2bf(v - __uint_as_float(((uint)h) << 16));
  }
  uint4 vh, vl;
  vh.x = (uint)hi[0] | ((uint)hi[1] << 16);
  vh.y = (uint)hi[2] | ((uint)hi[3] << 16);
  vh.z = (uint)hi[4] | ((uint)hi[5] << 16);
  vh.w = (uint)hi[6] | ((uint)hi[7] << 16);
  vl.x = (uint)lo[0] | ((uint)lo[1] << 16);
  vl.y = (uint)lo[2] | ((uint)lo[3] << 16);
  vl.z = (uint)lo[4] | ((uint)lo[5] << 16);
  vl.w = (uint)lo[6] | ((uint)lo[7] << 16);
  ((uint4*)(ws + OFF_BH))[fid * 64 + l] = vh;
  ((uint4*)(ws + OFF_BL))[fid * 64 + l] = vl;
}

// GEMM, fused A-conversion, 32 rows/wave (2 row-groups share B), depth-2
// pipeline, kc-slow grid + XCD swizzle so each XCD's L2 holds ~2 kc-chunks
// of B (~230 KB) -> B re-reads are L1/L2 hits.
// Block: 64 rows x 64 cols. Wave w: rows +((w>>1)*32), cols +((w&1)*32).
// acc layout (m89): col = lane&15, row = (lane>>4)*4 + reg.
__global__ __launch_bounds__(256, 3) void k_mm(
    const float* __restrict__ data, const float* __restrict__ mask,
    float* __restrict__ ws) {
  const short8* Bh = (const short8*)(ws + OFF_BH);
  const short8* Bl = (const short8*)(ws + OFF_BL);
  float* part = ws + OFF_PART;

  int p    = blockIdx.x;
  int vbid = (p & 7) * (NGRID / 8) + (p >> 3);   // bijective: 896 = 8*112
  int kc   = vbid / 64;          // slow index: blocks sharing kc colocate on XCD
  int rem  = vbid % 64;
  int mt   = rem >> 1;
  int nn   = rem & 1;

  int w   = threadIdx.x >> 6;
  int l   = threadIdx.x & 63;
  int r0  = mt * 64 + (w >> 1) * 32;      // wave's first row (2 groups of 16)
  int n0  = nn * 4 + (w & 1) * 2;         // wave's first nt (2 nt)
  int rowA = r0 + (l & 15);
  int g2   = (l >> 4) << 1;               // dim offset within k-step

  f32x4 acc[2][2];
#pragma unroll
  for (int g = 0; g < 2; g++)
#pragma unroll
    for (int i = 0; i < 2; i++) acc[g][i] = (f32x4){0.f, 0.f, 0.f, 0.f};

  const float* dp0 = data + (size_t)rowA * ND + g2;
  const float* mp0 = mask + (size_t)rowA * ND + g2;
  const float* dp1 = dp0 + 16 * ND;
  const float* mp1 = mp0 + 16 * ND;

  short8 Bhb[2][2], Blb[2][2];
  float2 xb[2][2], mb[2][2];

  auto loadstep = [&](int s, int buf) {
    int ks = kc * SPK + s;
    const short8* bh = Bh + ((size_t)(ks * 8) + n0) * 64 + l;
    const short8* bl = Bl + ((size_t)(ks * 8) + n0) * 64 + l;
    Bhb[buf][0] = bh[0];  Bhb[buf][1] = bh[64];
    Blb[buf][0] = bl[0];  Blb[buf][1] = bl[64];
    xb[buf][0] = *(const float2*)(dp0 + ks * 8);
    mb[buf][0] = *(const float2*)(mp0 + ks * 8);
    xb[buf][1] = *(const float2*)(dp1 + ks * 8);
    mb[buf][1] = *(const float2*)(mp1 + ks * 8);
  };

  loadstep(0, 0);

#pragma unroll
  for (int s = 0; s < SPK; s++) {
    const int cur = s & 1;
    const int nxt = cur ^ 1;
    if (s + 1 < SPK) loadstep(s + 1, nxt);   // in flight during this step

    short8 a_h[2], a_l[2];
#pragma unroll
    for (int g = 0; g < 2; g++) {
      float2 x = xb[cur][g], m = mb[cur][g];
      float mx0 = m.x * x.x, mq0 = mx0 * x.x;
      float mx1 = m.y * x.y, mq1 = mx1 * x.y;
      ushort h_q0 = f2bf(mq0), h_x0 = f2bf(mx0);
      ushort h_q1 = f2bf(mq1), h_x1 = f2bf(mx1);
      ushort h_m0 = (ushort)(__float_as_uint(m.x) >> 16);  // exact: m in {0,1}
      ushort h_m1 = (ushort)(__float_as_uint(m.y) >> 16);
      float r_q0 = mq0 - __uint_as_float(((uint)h_q0) << 16);
      float r_x0 = mx0 - __uint_as_float(((uint)h_x0) << 16);
      float r_q1 = mq1 - __uint_as_float(((uint)h_q1) << 16);
      float r_x1 = mx1 - __uint_as_float(((uint)h_x1) << 16);
      a_h[g][0] = (short)h_q0;       a_h[g][1] = (short)h_x0;
      a_h[g][2] = (short)h_m0;       a_h[g][3] = 0;
      a_h[g][4] = (short)h_q1;       a_h[g][5] = (short)h_x1;
      a_h[g][6] = (short)h_m1;       a_h[g][7] = 0;
      a_l[g][0] = (short)f2bf(r_q0); a_l[g][1] = (short)f2bf(r_x0);
      a_l[g][2] = 0;                 a_l[g][3] = 0;
      a_l[g][4] = (short)f2bf(r_q1); a_l[g][5] = (short)f2bf(r_x1);
      a_l[g][6] = 0;                 a_l[g][7] = 0;
    }

#pragma unroll
    for (int g = 0; g < 2; g++) {
      acc[g][0] = __builtin_amdgcn_mfma_f32_16x16x32_bf16(a_h[g], Bhb[cur][0], acc[g][0], 0, 0, 0);
      acc[g][0] = __builtin_amdgcn_mfma_f32_16x16x32_bf16(a_h[g], Blb[cur][0], acc[g][0], 0, 0, 0);
      acc[g][0] = __builtin_amdgcn_mfma_f32_16x16x32_bf16(a_l[g], Bhb[cur][0], acc[g][0], 0, 0, 0);
      acc[g][1] = __builtin_amdgcn_mfma_f32_16x16x32_bf16(a_h[g], Bhb[cur][1], acc[g][1], 0, 0, 0);
      acc[g][1] = __builtin_amdgcn_mfma_f32_16x16x32_bf16(a_h[g], Blb[cur][1], acc[g][1], 0, 0, 0);
      acc[g][1] = __builtin_amdgcn_mfma_f32_16x16x32_bf16(a_l[g], Bhb[cur][1], acc[g][1], 0, 0, 0);
    }
  }

#pragma unroll
  for (int g = 0; g < 2; g++)
#pragma unroll
    for (int ntl = 0; ntl < 2; ntl++)
#pragma unroll
      for (int r = 0; r < 4; r++) {
        int grow = r0 + g * 16 + ((l >> 4) << 2) + r;
        part[((size_t)kc * NB + grow) * NK + (n0 + ntl) * 16 + (l & 15)] = acc[g][ntl][r];
      }
}

// 2 rows per wave, float4 per lane (k-quad). Reduce KSPLIT partials, +log w,
// NaN fix, LSE with the reference's per-term +1e-8 (4e-8 per lane), exp.
__global__ __launch_bounds__(256) void k_final(
    const float* __restrict__ ws, float* __restrict__ out) {
  const float4* lw4   = (const float4*)(ws + OFF_LW);
  const float4* part4 = (const float4*)(ws + OFF_PART);
  int lane = threadIdx.x & 63;
  int wv   = threadIdx.x >> 6;
  int half = lane >> 5;
  int lk   = lane & 31;
  int b = blockIdx.x * 8 + wv * 2 + half;

  float4 s = make_float4(0.f, 0.f, 0.f, 0.f);
#pragma unroll
  for (int sp = 0; sp < KSPLIT; sp++) {
    float4 v = part4[((size_t)sp * NB + b) * 32 + lk];
    s.x += v.x; s.y += v.y; s.z += v.z; s.w += v.w;
  }
  float4 lv = lw4[lk];
  s.x += lv.x; s.y += lv.y; s.z += lv.z; s.w += lv.w;
  if (isnan(s.x)) s.x = 0.f;
  if (isnan(s.y)) s.y = 0.f;
  if (isnan(s.z)) s.z = 0.f;
  if (isnan(s.w)) s.w = 0.f;

  float mx = fmaxf(fmaxf(s.x, s.y), fmaxf(s.z, s.w));
#pragma unroll
  for (int off = 16; off; off >>= 1) mx = fmaxf(mx, __shfl_xor(mx, off));
  float sum = expf(s.x - mx) + expf(s.y - mx) + expf(s.z - mx) + expf(s.w - mx) + 4e-8f;
#pragma unroll
  for (int off = 16; off; off >>= 1) sum += __shfl_xor(sum, off);
  float lse = logf(sum) + mx;
  float4 o = make_float4(expf(s.x - lse), expf(s.y - lse),
                         expf(s.z - lse), expf(s.w - lse));
  ((float4*)out)[(size_t)b * 32 + lk] = o;
}

extern "C" void kernel_launch(void* const* d_in, const int* in_sizes, int n_in,
                              void* d_out, int out_size, void* d_ws, size_t ws_size,
                              hipStream_t stream) {
  const float* data = (const float*)d_in[0];
  const float* mask = (const float*)d_in[1];
  const float* wts  = (const float*)d_in[2];
  const float* mu   = (const float*)d_in[3];
  const float* cov  = (const float*)d_in[4];
  float* ws  = (float*)d_ws;
  float* out = (float*)d_out;

  k_prep<<<196, 256, 0, stream>>>(wts, mu, cov, ws);
  k_mm<<<NGRID, 256, 0, stream>>>(data, mask, ws);
  k_final<<<NB / 8, 256, 0, stream>>>(ws, out);
}

// Round 15
// 29.880 us; speedup vs baseline: 1.0965x; 1.0335x over previous
//
#include <hip/hip_runtime.h>
#include <math.h>

#define NB 2048
#define ND 784
#define NK 128
#define KP 3136            // 4*784: K = 4d+c, A slots {m*x^2, m*x, m, 0}
#define NSTEP 98           // KP/32 k-steps
#define KSPLIT 14          // K-chunks -> partials
#define SPK 7              // k-steps per chunk
#define MT 64              // rows per k_mm block (4 waves x 16 rows)
#define NHALF 2            // N-split: each wave does 4 nt = 64 cols

typedef __attribute__((ext_vector_type(8))) short short8;
typedef __attribute__((ext_vector_type(4))) float f32x4;

// ws float offsets:
#define OFF_LW   0
#define OFF_PART 128
#define N_PART   (KSPLIT * NB * NK)       // 3,670,016 floats (14.7 MB)
#define OFF_BH   (OFF_PART + N_PART)
#define N_B_F    (NSTEP * 8 * 64 * 4)     // 200,704 float slots per table
#define OFF_BL   (OFF_BH + N_B_F)

__device__ inline ushort f2bf(float f) {   // round-to-nearest-even f32->bf16
  uint u = __float_as_uint(f);
  return (ushort)((u + 0x7FFFu + ((u >> 16) & 1u)) >> 16);
}

// B-prep + log w. Fragment fid = ks*8 + nt; lane l holds
// B[K = ks*32 + (l>>4)*8 + j][n = nt*16 + (l&15)], j=0..7, K = 4d+c:
// c==0 -> -1/2c, c==1 -> mu/c, c==2 -> -mu^2/2c - ln(c)/2, c==3 -> 0.
__global__ __launch_bounds__(256) void k_prep(
    const float* __restrict__ w, const float* __restrict__ mu,
    const float* __restrict__ cov, float* __restrict__ ws) {
  int tid = blockIdx.x * 256 + threadIdx.x;   // 0..50175
  if (tid < NK) ws[OFF_LW + tid] = logf(w[tid]);
  int l   = tid & 63;
  int fid = tid >> 6;          // 0..783
  int nt  = fid & 7;
  int ks  = fid >> 3;          // 0..97
  int n   = nt * 16 + (l & 15);
  int K0  = ks * 32 + ((l >> 4) << 3);
  ushort hi[8], lo[8];
#pragma unroll
  for (int j = 0; j < 8; j++) {
    int K = K0 + j;
    int d = K >> 2;
    int c = K & 3;
    float cv = cov[n * ND + d];
    float mv = mu[n * ND + d];
    float v = (c == 0) ? (-0.5f / cv)
            : (c == 1) ? (mv / cv)
            : (c == 2) ? (-mv * mv * 0.5f / cv - 0.5f * logf(cv))
                       : 0.f;
    ushort h = f2bf(v);
    hi[j] = h;
    lo[j] = f2bf(v - __uint_as_float(((uint)h) << 16));
  }
  uint4 vh, vl;
  vh.x = (uint)hi[0] | ((uint)hi[1] << 16);
  vh.y = (uint)hi[2] | ((uint)hi[3] << 16);
  vh.z = (uint)hi[4] | ((uint)hi[5] << 16);
  vh.w = (uint)hi[6] | ((uint)hi[7] << 16);
  vl.x = (uint)lo[0] | ((uint)lo[1] << 16);
  vl.y = (uint)lo[2] | ((uint)lo[3] << 16);
  vl.z = (uint)lo[4] | ((uint)lo[5] << 16);
  vl.w = (uint)lo[6] | ((uint)lo[7] << 16);
  ((uint4*)(ws + OFF_BH))[fid * 64 + l] = vh;
  ((uint4*)(ws + OFF_BL))[fid * 64 + l] = vl;
}

// GEMM, PRE-CONVERTED A: all SPK k-steps' A fragments are built in registers
// before the k-loop, so the loop is pure {8 batched B loads -> 12 MFMAs} with
// no VALU on the load->MFMA critical path. Geometry = R12 (best point):
// grid = 32 mt x NHALF x KSPLIT = 896 blocks, 4 waves, 3.5 waves/SIMD.
// Wave: 16 rows x 64 cols (nt = nh*4..nh*4+3) x SPK k-steps.
// acc layout (m89): col = lane&15, row = (lane>>4)*4 + reg.
__global__ __launch_bounds__(256, 4) void k_mm(
    const float* __restrict__ data, const float* __restrict__ mask,
    float* __restrict__ ws) {
  const short8* Bh = (const short8*)(ws + OFF_BH);
  const short8* Bl = (const short8*)(ws + OFF_BL);
  float* part = ws + OFF_PART;

  int bid = blockIdx.x;
  int mt  = bid / (NHALF * KSPLIT);
  int rem = bid % (NHALF * KSPLIT);
  int nh  = rem / KSPLIT;
  int kc  = rem % KSPLIT;
  int w   = threadIdx.x >> 6;
  int l   = threadIdx.x & 63;
  int r0  = mt * MT + w * 16;
  int rowA = r0 + (l & 15);
  int g2   = (l >> 4) << 1;     // dim offset within k-step: 0,2,4,6
  int n0   = nh * 4;            // first nt of this wave

  const float* dp = data + (size_t)rowA * ND + g2;
  const float* mp = mask + (size_t)rowA * ND + g2;

  // ---- pre-load all x/m for this chunk (14 independent 8B loads)
  float2 xs[SPK], ms[SPK];
#pragma unroll
  for (int s = 0; s < SPK; s++) {
    int ks = kc * SPK + s;
    xs[s] = *(const float2*)(dp + ks * 8);
    ms[s] = *(const float2*)(mp + ks * 8);
  }

  // ---- pre-convert all A fragments (off the k-loop critical path)
  short8 ah[SPK], al[SPK];
#pragma unroll
  for (int s = 0; s < SPK; s++) {
    float2 x = xs[s], m = ms[s];
    float mx0 = m.x * x.x, mq0 = mx0 * x.x;
    float mx1 = m.y * x.y, mq1 = mx1 * x.y;
    ushort h_q0 = f2bf(mq0), h_x0 = f2bf(mx0);
    ushort h_q1 = f2bf(mq1), h_x1 = f2bf(mx1);
    ushort h_m0 = (ushort)(__float_as_uint(m.x) >> 16);  // exact: m in {0,1}
    ushort h_m1 = (ushort)(__float_as_uint(m.y) >> 16);
    float r_q0 = mq0 - __uint_as_float(((uint)h_q0) << 16);
    float r_x0 = mx0 - __uint_as_float(((uint)h_x0) << 16);
    float r_q1 = mq1 - __uint_as_float(((uint)h_q1) << 16);
    float r_x1 = mx1 - __uint_as_float(((uint)h_x1) << 16);
    ah[s][0] = (short)h_q0;       ah[s][1] = (short)h_x0;
    ah[s][2] = (short)h_m0;       ah[s][3] = 0;
    ah[s][4] = (short)h_q1;       ah[s][5] = (short)h_x1;
    ah[s][6] = (short)h_m1;       ah[s][7] = 0;
    al[s][0] = (short)f2bf(r_q0); al[s][1] = (short)f2bf(r_x0);
    al[s][2] = 0;                 al[s][3] = 0;
    al[s][4] = (short)f2bf(r_q1); al[s][5] = (short)f2bf(r_x1);
    al[s][6] = 0;                 al[s][7] = 0;
  }

  f32x4 acc[4];
#pragma unroll
  for (int i = 0; i < 4; i++) acc[i] = (f32x4){0.f, 0.f, 0.f, 0.f};

#pragma unroll
  for (int s = 0; s < SPK; s++) {
    int ks = kc * SPK + s;
    const short8* bh = Bh + ((size_t)(ks * 8) + n0) * 64 + l;
    const short8* bl = Bl + ((size_t)(ks * 8) + n0) * 64 + l;
    // batch all 8 B loads (one latency window, TLP-hidden at 3.5 w/SIMD)
    short8 b_h0 = bh[0], b_h1 = bh[64], b_h2 = bh[128], b_h3 = bh[192];
    short8 b_l0 = bl[0], b_l1 = bl[64], b_l2 = bl[128], b_l3 = bl[192];

    acc[0] = __builtin_amdgcn_mfma_f32_16x16x32_bf16(ah[s], b_h0, acc[0], 0, 0, 0);
    acc[0] = __builtin_amdgcn_mfma_f32_16x16x32_bf16(ah[s], b_l0, acc[0], 0, 0, 0);
    acc[0] = __builtin_amdgcn_mfma_f32_16x16x32_bf16(al[s], b_h0, acc[0], 0, 0, 0);
    acc[1] = __builtin_amdgcn_mfma_f32_16x16x32_bf16(ah[s], b_h1, acc[1], 0, 0, 0);
    acc[1] = __builtin_amdgcn_mfma_f32_16x16x32_bf16(ah[s], b_l1, acc[1], 0, 0, 0);
    acc[1] = __builtin_amdgcn_mfma_f32_16x16x32_bf16(al[s], b_h1, acc[1], 0, 0, 0);
    acc[2] = __builtin_amdgcn_mfma_f32_16x16x32_bf16(ah[s], b_h2, acc[2], 0, 0, 0);
    acc[2] = __builtin_amdgcn_mfma_f32_16x16x32_bf16(ah[s], b_l2, acc[2], 0, 0, 0);
    acc[2] = __builtin_amdgcn_mfma_f32_16x16x32_bf16(al[s], b_h2, acc[2], 0, 0, 0);
    acc[3] = __builtin_amdgcn_mfma_f32_16x16x32_bf16(ah[s], b_h3, acc[3], 0, 0, 0);
    acc[3] = __builtin_amdgcn_mfma_f32_16x16x32_bf16(ah[s], b_l3, acc[3], 0, 0, 0);
    acc[3] = __builtin_amdgcn_mfma_f32_16x16x32_bf16(al[s], b_h3, acc[3], 0, 0, 0);
  }

#pragma unroll
  for (int ntl = 0; ntl < 4; ntl++)
#pragma unroll
    for (int r = 0; r < 4; r++) {
      int grow = r0 + ((l >> 4) << 2) + r;
      part[((size_t)kc * NB + grow) * NK + (n0 + ntl) * 16 + (l & 15)] = acc[ntl][r];
    }
}

// 2 rows per wave, float4 per lane (k-quad). Reduce KSPLIT partials, +log w,
// NaN fix, LSE with the reference's per-term +1e-8 (4e-8 per lane), exp.
__global__ __launch_bounds__(256) void k_final(
    const float* __restrict__ ws, float* __restrict__ out) {
  const float4* lw4   = (const float4*)(ws + OFF_LW);
  const float4* part4 = (const float4*)(ws + OFF_PART);
  int lane = threadIdx.x & 63;
  int wv   = threadIdx.x >> 6;
  int half = lane >> 5;
  int lk   = lane & 31;
  int b = blockIdx.x * 8 + wv * 2 + half;

  float4 s = make_float4(0.f, 0.f, 0.f, 0.f);
#pragma unroll
  for (int sp = 0; sp < KSPLIT; sp++) {
    float4 v = part4[((size_t)sp * NB + b) * 32 + lk];
    s.x += v.x; s.y += v.y; s.z += v.z; s.w += v.w;
  }
  float4 lv = lw4[lk];
  s.x += lv.x; s.y += lv.y; s.z += lv.z; s.w += lv.w;
  if (isnan(s.x)) s.x = 0.f;
  if (isnan(s.y)) s.y = 0.f;
  if (isnan(s.z)) s.z = 0.f;
  if (isnan(s.w)) s.w = 0.f;

  float mx = fmaxf(fmaxf(s.x, s.y), fmaxf(s.z, s.w));
#pragma unroll
  for (int off = 16; off; off >>= 1) mx = fmaxf(mx, __shfl_xor(mx, off));
  float sum = expf(s.x - mx) + expf(s.y - mx) + expf(s.z - mx) + expf(s.w - mx) + 4e-8f;
#pragma unroll
  for (int off = 16; off; off >>= 1) sum += __shfl_xor(sum, off);
  float lse = logf(sum) + mx;
  float4 o = make_float4(expf(s.x - lse), expf(s.y - lse),
                         expf(s.z - lse), expf(s.w - lse));
  ((float4*)out)[(size_t)b * 32 + lk] = o;
}

extern "C" void kernel_launch(void* const* d_in, const int* in_sizes, int n_in,
                              void* d_out, int out_size, void* d_ws, size_t ws_size,
                              hipStream_t stream) {
  const float* data = (const float*)d_in[0];
  const float* mask = (const float*)d_in[1];
  const float* wts  = (const float*)d_in[2];
  const float* mu   = (const float*)d_in[3];
  const float* cov  = (const float*)d_in[4];
  float* ws  = (float*)d_ws;
  float* out = (float*)d_out;

  k_prep<<<196, 256, 0, stream>>>(wts, mu, cov, ws);
  k_mm<<<32 * NHALF * KSPLIT, 256, 0, stream>>>(data, mask, ws);
  k_final<<<NB / 8, 256, 0, stream>>>(ws, out);
}